// Round 13
// baseline (313.854 us; speedup 1.0000x reference)
//
#include <hip/hip_runtime.h>

typedef __bf16 bf16;
typedef __attribute__((ext_vector_type(4))) __bf16 bf16x4;
typedef __attribute__((ext_vector_type(8))) __bf16 bf16x8;
typedef __attribute__((ext_vector_type(4))) float f32x4;
typedef __attribute__((ext_vector_type(16))) float f32x16;
typedef unsigned int u32;

#define D_MODEL 1024
#define SEQ_L   2048
#define NHEAD   16
#define HDIM    64
#define MROWS   4096   // B*L

// 1/sqrt(64) * log2(e): folded into Wq/bq so attn can use raw v_exp_f32 (exp2)
#define S_SCALE 0.18033688f

// ---- workspace layout (bf16-element offsets) ----
#define FEAT_OFF  512u
#define WQ_OFF    (FEAT_OFF + 4194304u)
#define WK_OFF    (WQ_OFF + 1048576u)
#define WV_OFF    (WK_OFF + 1048576u)
#define BQ_OFF    (WV_OFF + 1048576u)
#define BK_OFF    (BQ_OFF + 1024u)
#define BV_OFF    (BK_OFF + 1024u)
#define Q_OFF     (BV_OFF + 1024u)
#define K_OFF     (Q_OFF + 4194304u)
#define V_OFF     (K_OFF + 4194304u)     // Vt: [b][dout(1024)][token(2048)]

// async global->LDS, 16B per lane; LDS dest = wave-uniform base + lane*16
typedef const __attribute__((address_space(1))) u32* gp_t;
typedef __attribute__((address_space(3))) u32* lp_t;
__device__ __forceinline__ void ld16(const bf16* g, bf16* l) {
    __builtin_amdgcn_global_load_lds((gp_t)g, (lp_t)l, 16, 0, 0);
}

// ---------------------------------------------------------------------------
// Convert f32 inputs -> bf16 in ws. Wq/bq pre-scaled by S_SCALE (exact-count
// rounding: one f32->bf16 round either way). Flat grid: 7171 x 256 x 4.
// ---------------------------------------------------------------------------
__global__ void convert_in(const float* __restrict__ feat,
                           const float* __restrict__ wq, const float* __restrict__ wk,
                           const float* __restrict__ wv,
                           const float* __restrict__ bq, const float* __restrict__ bk,
                           const float* __restrict__ bv,
                           bf16* __restrict__ ws) {
    const int bid = blockIdx.x;
    const float* src; bf16* dst; int off; float sc = 1.0f;
    if (bid < 4096)      { src = feat; dst = ws + FEAT_OFF; off = bid * 1024; }
    else if (bid < 5120) { src = wq;   dst = ws + WQ_OFF;   off = (bid - 4096) * 1024; sc = S_SCALE; }
    else if (bid < 6144) { src = wk;   dst = ws + WK_OFF;   off = (bid - 5120) * 1024; }
    else if (bid < 7168) { src = wv;   dst = ws + WV_OFF;   off = (bid - 6144) * 1024; }
    else if (bid == 7168){ src = bq;   dst = ws + BQ_OFF;   off = 0; sc = S_SCALE; }
    else if (bid == 7169){ src = bk;   dst = ws + BK_OFF;   off = 0; }
    else                 { src = bv;   dst = ws + BV_OFF;   off = 0; }
    int idx = off + threadIdx.x * 4;
    float4 v = *(const float4*)(src + idx);
    bf16x4 o;
    o[0] = (bf16)(v.x * sc);
    o[1] = (bf16)(v.y * sc);
    o[2] = (bf16)(v.z * sc);
    o[3] = (bf16)(v.w * sc);
    *(bf16x4*)(dst + idx) = o;          // one 8B store (coalesced)
}

// ---------------------------------------------------------------------------
// QKV projection v3 (rounds 8+11): Q,K fused with BK=32 double-buffered
// prefetch; zi=1: Vt = Wv*X^T with BK=64 double-buffered.
// Grid (32,8,2) = 512 blocks, 64KB LDS -> 2 blocks/CU.
// ---------------------------------------------------------------------------
__global__ __launch_bounds__(256, 2) void qkv_gemm(const bf16* __restrict__ ws,
                                                   bf16* __restrict__ wsw,
                                                   const int* __restrict__ mask) {
    __shared__ bf16 smem[32768];               // 64KB pool
    const int zi   = blockIdx.z;
    const int t    = threadIdx.x;
    const int lane = t & 63;
    const int wave = t >> 6;
    const int quad = lane >> 4;
    const int l16  = lane & 15;
    const int wrow = (wave >> 1) * 64;
    const int wcol = (wave & 1) * 64;

    if (zi == 0) {
        // ================= fused Q,K (BK=32, double-buffered) =================
        bf16* Ab = smem;                       // + buf*4096
        bf16* Bq = smem + 8192;
        bf16* Bk = smem + 16384;
        const bf16* X   = ws + FEAT_OFF;
        const bf16* Wq  = ws + WQ_OFF;         // pre-scaled by S_SCALE
        const bf16* Wk  = ws + WK_OFF;
        const int m0 = blockIdx.x * 128;       // token rows
        const int n0 = blockIdx.y * 128;       // output cols

        const int r4  = lane >> 2;             // row-in-chunk 0..15
        const int sgq = (lane & 3) ^ ((lane >> 3) & 3);   // pre-swizzled seg

        f32x4 aq[4][4], ak[4][4];
        for (int mi = 0; mi < 4; ++mi)
            for (int ni = 0; ni < 4; ++ni) {
                aq[mi][ni] = (f32x4){0.f, 0.f, 0.f, 0.f};
                ak[mi][ni] = (f32x4){0.f, 0.f, 0.f, 0.f};
            }

#define STAGEQK(bb, k0)                                                        \
    do {                                                                       \
        _Pragma("unroll")                                                      \
        for (int i = 0; i < 2; ++i) {                                          \
            int ch  = wave * 2 + i;                                            \
            int row = ch * 16 + r4;                                            \
            ld16(X  + (size_t)(m0 + row) * D_MODEL + (k0) + sgq * 8,           \
                 Ab + (bb) * 4096 + ch * 512);                                 \
            ld16(Wq + (size_t)(n0 + row) * D_MODEL + (k0) + sgq * 8,           \
                 Bq + (bb) * 4096 + ch * 512);                                 \
            ld16(Wk + (size_t)(n0 + row) * D_MODEL + (k0) + sgq * 8,           \
                 Bk + (bb) * 4096 + ch * 512);                                 \
        }                                                                      \
    } while (0)

        STAGEQK(0, 0);
        __syncthreads();

        int cur = 0;
        for (int k0 = 0; k0 < D_MODEL; k0 += 32) {
            // prefetch next step FIRST (in flight under the 32 MFMAs below)
            if (k0 + 32 < D_MODEL) STAGEQK(cur ^ 1, k0 + 32);

            bf16x8 af[4], bq8[4], bk8[4];
#pragma unroll
            for (int mi = 0; mi < 4; ++mi) {
                int row  = wrow + mi * 16 + l16;
                int phys = quad ^ ((row >> 1) & 3);
                af[mi] = *(const bf16x8*)(&Ab[cur * 4096 + row * 32 + phys * 8]);
            }
#pragma unroll
            for (int ni = 0; ni < 4; ++ni) {
                int row  = wcol + ni * 16 + l16;
                int phys = quad ^ ((row >> 1) & 3);
                bq8[ni] = *(const bf16x8*)(&Bq[cur * 4096 + row * 32 + phys * 8]);
                bk8[ni] = *(const bf16x8*)(&Bk[cur * 4096 + row * 32 + phys * 8]);
            }
#pragma unroll
            for (int mi = 0; mi < 4; ++mi)
#pragma unroll
                for (int ni = 0; ni < 4; ++ni)
                    aq[mi][ni] = __builtin_amdgcn_mfma_f32_16x16x32_bf16(
                        af[mi], bq8[ni], aq[mi][ni], 0, 0, 0);
#pragma unroll
            for (int mi = 0; mi < 4; ++mi)
#pragma unroll
                for (int ni = 0; ni < 4; ++ni)
                    ak[mi][ni] = __builtin_amdgcn_mfma_f32_16x16x32_bf16(
                        af[mi], bk8[ni], ak[mi][ni], 0, 0, 0);

            __syncthreads();    // joins + drains the in-flight prefetch
            cur ^= 1;
        }
#undef STAGEQK

        bf16* Yq = wsw + Q_OFF;
        bf16* Yk = wsw + K_OFF;
        const bf16* bq = ws + BQ_OFF;
        const bf16* bk = ws + BK_OFF;
#pragma unroll
        for (int ni = 0; ni < 4; ++ni) {
            int col = n0 + wcol + ni * 16 + l16;
            float bqf = (float)bq[col];
            float bkf = (float)bk[col];
#pragma unroll
            for (int mi = 0; mi < 4; ++mi) {
                int rowb = m0 + wrow + mi * 16 + quad * 4;
#pragma unroll
                for (int r = 0; r < 4; ++r) {
                    Yq[(size_t)(rowb + r) * D_MODEL + col] = (bf16)(aq[mi][ni][r] + bqf);
                    float v = ak[mi][ni][r] + bkf;
                    if (mask[rowb + r] == 0) v = 0.f;             // zero masked K rows
                    Yk[(size_t)(rowb + r) * D_MODEL + col] = (bf16)v;
                }
            }
        }
    } else {
        // ================= Vt = Wv*X^T (BK=64, double-buffered) ==============
        bf16* Ab = smem;                       // + buf*8192
        bf16* Bb = smem + 16384;
        const bf16* Amat = ws + WV_OFF;
        const bf16* Bmat = ws + FEAT_OFF;
        const bf16* bias = ws + BV_OFF;
        bf16* Y = wsw + V_OFF;
        const int m0 = blockIdx.y * 128;       // dout rows
        const int n0 = blockIdx.x * 128;       // token cols

        const int r8 = lane >> 3;
        const int sl = lane & 7;
        const int sg = sl ^ r8;

        f32x4 acc[4][4];
        for (int mi = 0; mi < 4; ++mi)
            for (int ni = 0; ni < 4; ++ni)
                acc[mi][ni] = (f32x4){0.f, 0.f, 0.f, 0.f};

#define STAGEV(bb, k0)                                                         \
    do {                                                                       \
        _Pragma("unroll")                                                      \
        for (int i = 0; i < 4; ++i) {                                          \
            int ch  = wave * 4 + i;                                            \
            int row = ch * 8 + r8;                                             \
            ld16(Amat + (size_t)(m0 + row) * D_MODEL + (k0) + sg * 8,          \
                 Ab + (bb) * 8192 + ch * 512);                                 \
            ld16(Bmat + (size_t)(n0 + row) * D_MODEL + (k0) + sg * 8,          \
                 Bb + (bb) * 8192 + ch * 512);                                 \
        }                                                                      \
    } while (0)

        STAGEV(0, 0);
        __syncthreads();

        int cur = 0;
        for (int k0 = 0; k0 < D_MODEL; k0 += 64) {
            if (k0 + 64 < D_MODEL) STAGEV(cur ^ 1, k0 + 64);

#pragma unroll
            for (int kk = 0; kk < 2; ++kk) {
                const int sgb = quad + kk * 4;
                bf16x8 af[4], bfr[4];
#pragma unroll
                for (int mi = 0; mi < 4; ++mi) {
                    int row = wrow + mi * 16 + l16;
                    af[mi] = *(const bf16x8*)(
                        &Ab[cur * 8192 + row * 64 + ((sgb ^ (row & 7)) << 3)]);
                }
#pragma unroll
                for (int ni = 0; ni < 4; ++ni) {
                    int row = wcol + ni * 16 + l16;
                    bfr[ni] = *(const bf16x8*)(
                        &Bb[cur * 8192 + row * 64 + ((sgb ^ (row & 7)) << 3)]);
                }
#pragma unroll
                for (int mi = 0; mi < 4; ++mi)
#pragma unroll
                    for (int ni = 0; ni < 4; ++ni)
                        acc[mi][ni] = __builtin_amdgcn_mfma_f32_16x16x32_bf16(
                            af[mi], bfr[ni], acc[mi][ni], 0, 0, 0);
            }

            __syncthreads();    // joins + drains the in-flight prefetch
            cur ^= 1;
        }
#undef STAGEV

#pragma unroll
        for (int mi = 0; mi < 4; ++mi) {
#pragma unroll
            for (int r = 0; r < 4; ++r) {
                int rowv = m0 + wrow + mi * 16 + quad * 4 + r;   // dout
                float bvf = (float)bias[rowv];
#pragma unroll
                for (int ni = 0; ni < 4; ++ni) {
                    int col = n0 + wcol + ni * 16 + l16;          // token
                    float v = acc[mi][ni][r] + bvf;
                    if (mask[col] == 0) v = 0.f;                  // zero masked Vt cols
                    size_t addr = (size_t)(col >> 11) * 2097152u +
                                  (size_t)rowv * 2048u + (col & 2047);
                    Y[addr] = (bf16)v;
                }
            }
        }
    }
}

// ---------------------------------------------------------------------------
// Flash attention v19 = v17 (round-12: in-block key-split + mask-hoist +
// setprio, attn 48.9us) with K moved from LDS to a REGISTER prefetch:
//  - K fragments are per-wave private (no cross-wave sharing existed), so the
//    LDS round-trip bought only bank conflicts + a ds_read chain head. Each
//    iter t now issues 8 global_load_dwordx4 for tile t+1 into named regs
//    (kA/kB ping-pong); the full iteration body + the barrier's vmcnt drain
//    cover the L2 latency (v12's no-LDS failure was ZERO prefetch distance —
//    this has a full iteration).
//  - QK(t) issues immediately after the barrier from registers (no lgkm wait
//    at the chain head); K ds_reads vanish (bank conflicts ~halve).
//  - V unchanged (LDS double-buffered, same swizzle). LDS 64KB -> 33KB.
//  - epilogue: o-exchange via the 32KB V pool; per-q l via separate 1KB exl.
// grid (bh, qt) = (32, 16) = 512 blocks x 512 thr, 16 waves/CU.
// ---------------------------------------------------------------------------
__global__ __launch_bounds__(512, 4) void attn_kernel(
    const bf16* __restrict__ ws,
    const int* __restrict__ mask, float* __restrict__ out) {
    const int bh  = blockIdx.x;          // 0..31
    const int qt  = blockIdx.y;          // 0..15 (128 q-rows per block)
    const int b   = bh >> 4, h = bh & 15;
    const int t    = threadIdx.x;
    const int lane = t & 63;
    const int wave = t >> 6;            // 0..7
    const int qh   = wave & 3;          // q sub-tile within block
    const int kh   = wave >> 2;         // key half
    const int half = lane >> 5;
    const int l31  = lane & 31;
    const int kt0  = kh * 1024;

    __shared__ bf16 Vs[2][2][4096];     // 32KB: [kh][buf][64x64], seg-swizzled
    __shared__ float exl[256];          // 1KB: per-q l partials [kh][128]
    bf16* Vsp = &Vs[0][0][0];

    const bf16* Qh  = ws + Q_OFF + (size_t)(b * SEQ_L) * D_MODEL + h * HDIM;
    const bf16* Kh  = ws + K_OFF + (size_t)(b * SEQ_L) * D_MODEL + h * HDIM;
    const bf16* Vth = ws + V_OFF + (size_t)b * 2097152u + (size_t)(h * HDIM) * SEQ_L;

    // ---- mask loads FIRST (in-order VMEM: consuming them later won't drain
    //      the staging loads issued after)
    int mvv[16];
#pragma unroll
    for (int i = 0; i < 16; ++i)
        mvv[i] = mask[b * SEQ_L + kt0 + i * 64 + lane];

    // staging geometry for V (qh plays v9's wave role inside the kh-group)
    const int srow = (lane >> 3);            // 0..7
    const int sg   = (lane & 7) ^ srow;      // swizzled global segment

#define STAGE_V(bb, kt)                                                        \
    do {                                                                       \
        _Pragma("unroll")                                                      \
        for (int i = 0; i < 2; ++i) {                                          \
            int row = i * 32 + qh * 8 + srow;                                  \
            ld16(Vth + (size_t)row * SEQ_L + (kt) + sg * 8,                    \
                 Vsp + (kh * 2 + (bb)) * 4096 + i * 2048 + qh * 512);          \
        }                                                                      \
    } while (0)

// K register prefetch: 8 bf16x8 fragments (ktile = kk>>2, ks = kk&3)
#define KLOAD(dst, kt)                                                         \
    do {                                                                       \
        _Pragma("unroll")                                                      \
        for (int kk = 0; kk < 8; ++kk) {                                       \
            const int ktile = kk >> 2, ks = kk & 3;                            \
            dst[kk] = *(const bf16x8*)(Kh +                                    \
                (size_t)((kt) + ktile * 32 + l31) * D_MODEL +                  \
                ks * 16 + half * 8);                                           \
        }                                                                      \
    } while (0)

    bf16x8 kA[8], kB[8];

    // prologue: V tile 0 -> LDS, K tile 0 -> regs
    STAGE_V(0, kt0);
    KLOAD(kA, kt0);

    // masked-key overcount (tile-order independent), consumed pre-loop
    int nm = 0;
#pragma unroll
    for (int i = 0; i < 16; ++i)
        nm += (int)__popcll(__ballot(mvv[i] != 0));

    // Q fragments as B-operand (n=q=l31, k=d); scale already folded into Wq.
    const int qrow0 = qt * 128 + qh * 32;
    bf16x8 qf[4];
#pragma unroll
    for (int ks = 0; ks < 4; ++ks)
        qf[ks] = *(const bf16x8*)(Qh + (size_t)(qrow0 + l31) * D_MODEL
                                  + ks * 16 + half * 8);

    bf16x8 ones;
#pragma unroll
    for (int j = 0; j < 8; ++j) ones[j] = (bf16)1.0f;

    f32x16 o[2], lacc;
#pragma unroll
    for (int i = 0; i < 16; ++i) { o[0][i] = 0.f; o[1][i] = 0.f; lacc[i] = 0.f; }

    __syncthreads();    // drains V stage + K loads: kA/V buf0 ready

#define ATTN_ITER(IT, KC, KN, BUF, PREF)                                       \
    do {                                                                       \
        const int kt = kt0 + (IT) * 64;                                        \
        if (PREF) {                                                            \
            STAGE_V((BUF) ^ 1, kt + 64);                                       \
            KLOAD(KN, kt + 64);                                                \
        }                                                                      \
        /* S^T = K * Q^T straight from registers (no LDS on the chain head) */ \
        f32x16 st[2];                                                          \
        __builtin_amdgcn_s_setprio(1);                                         \
        _Pragma("unroll")                                                      \
        for (int ktile = 0; ktile < 2; ++ktile) {                              \
            _Pragma("unroll")                                                  \
            for (int i = 0; i < 16; ++i) st[ktile][i] = 0.f;                   \
            _Pragma("unroll")                                                  \
            for (int ks = 0; ks < 4; ++ks)                                     \
                st[ktile] = __builtin_amdgcn_mfma_f32_32x32x16_bf16(           \
                    KC[ktile * 4 + ks], qf[ks], st[ktile], 0, 0, 0);           \
        }                                                                      \
        __builtin_amdgcn_s_setprio(0);                                         \
        /* P = exp2(S^T); masked keys give st=0 -> p=1 (corrected in l) */     \
        bf16x4 pk[2][4];                                                       \
        _Pragma("unroll")                                                      \
        for (int ktile = 0; ktile < 2; ++ktile) {                              \
            _Pragma("unroll")                                                  \
            for (int g = 0; g < 4; ++g) {                                      \
                bf16x4 pkv;                                                    \
                _Pragma("unroll")                                              \
                for (int j = 0; j < 4; ++j)                                    \
                    pkv[j] = (bf16)__builtin_amdgcn_exp2f(st[ktile][g*4+j]);   \
                pk[ktile][g] = pkv;                                            \
            }                                                                  \
        }                                                                      \
        /* C->A layout via one shfl_xor(32) per fragment */                    \
        bf16x8 pf[4];                                                          \
        _Pragma("unroll")                                                      \
        for (int ks = 0; ks < 4; ++ks) {                                       \
            const int k1 = ks & 1, kt2 = ks >> 1;                              \
            uint2 a  = __builtin_bit_cast(uint2, pk[kt2][2 * k1]);             \
            uint2 bb = __builtin_bit_cast(uint2, pk[kt2][2 * k1 + 1]);         \
            uint2 keep, send;                                                  \
            keep.x = half ? bb.x : a.x;  keep.y = half ? bb.y : a.y;           \
            send.x = half ? a.x : bb.x;  send.y = half ? a.y : bb.y;           \
            uint2 recv;                                                        \
            recv.x = (unsigned)__shfl_xor((int)send.x, 32);                    \
            recv.y = (unsigned)__shfl_xor((int)send.y, 32);                    \
            uint4 frag;                                                        \
            frag.x = half ? recv.x : keep.x;                                   \
            frag.y = half ? recv.y : keep.y;                                   \
            frag.z = half ? keep.x : recv.x;                                   \
            frag.w = half ? keep.y : recv.y;                                   \
            pf[ks] = __builtin_bit_cast(bf16x8, frag);                         \
        }                                                                      \
        /* O += P*V ; l += P*ones */                                           \
        const bf16* Vcur = Vsp + (kh * 2 + (BUF)) * 4096;                      \
        __builtin_amdgcn_s_setprio(1);                                         \
        _Pragma("unroll")                                                      \
        for (int ks = 0; ks < 4; ++ks)                                         \
            lacc = __builtin_amdgcn_mfma_f32_32x32x16_bf16(                    \
                pf[ks], ones, lacc, 0, 0, 0);                                  \
        _Pragma("unroll")                                                      \
        for (int dt = 0; dt < 2; ++dt) {                                       \
            _Pragma("unroll")                                                  \
            for (int ks = 0; ks < 4; ++ks) {                                   \
                const int row  = dt * 32 + l31;                                \
                const int slot = (ks * 2 + half) ^ (l31 & 7);                  \
                bf16x8 vf = *(const bf16x8*)(&Vcur[row * 64 + slot * 8]);      \
                o[dt] = __builtin_amdgcn_mfma_f32_32x32x16_bf16(               \
                    pf[ks], vf, o[dt], 0, 0, 0);                               \
            }                                                                  \
        }                                                                      \
        __builtin_amdgcn_s_setprio(0);                                         \
        __syncthreads();   /* joins + drains V stage AND K reg loads */        \
    } while (0)

    for (int ith = 0; ith < 8; ++ith) {
        ATTN_ITER(2 * ith,     kA, kB, 0, 1);          // 2*ith <= 14: always prefetch
        ATTN_ITER(2 * ith + 1, kB, kA, 1, (ith < 7));  // last iter: no prefetch
    }
#undef ATTN_ITER
#undef KLOAD
#undef STAGE_V

    // ---- in-block cross-half reduction.
    //      per-q l scalars via exl (lacc[r] is column-replicated); o partials
    //      via the dead 32KB V pool as a [32][256] f32 exchange.
    const float corr = (float)(1024 - nm);
    float* ex = (float*)Vsp;
    const int slot = qh * 64 + lane;
    if (l31 == 0) {
#pragma unroll
        for (int r = 0; r < 16; ++r) {
            const int q32 = (r & 3) + 8 * (r >> 2) + 4 * half;
            exl[kh * 128 + qh * 32 + q32] = lacc[r] - corr;
        }
    }
    if (kh == 1) {
#pragma unroll
        for (int r = 0; r < 16; ++r) {
            ex[r * 256 + slot]        = o[0][r];
            ex[(16 + r) * 256 + slot] = o[1][r];
        }
    }
    __syncthreads();
    if (kh == 0) {
#pragma unroll
        for (int r = 0; r < 16; ++r) {
            const int q32 = (r & 3) + 8 * (r >> 2) + 4 * half;
            const int q = qrow0 + q32;
            const size_t base = ((size_t)(b * SEQ_L + q)) * D_MODEL + h * HDIM;
            const float l  = exl[qh * 32 + q32] + exl[128 + qh * 32 + q32];
            const float rl = 1.0f / fmaxf(l, 1e-30f);
            out[base + l31]      = (o[0][r] + ex[r * 256 + slot]) * rl;
            out[base + 32 + l31] = (o[1][r] + ex[(16 + r) * 256 + slot]) * rl;
        }
    }
}

extern "C" void kernel_launch(void* const* d_in, const int* in_sizes, int n_in,
                              void* d_out, int out_size, void* d_ws, size_t ws_size,
                              hipStream_t stream) {
    const float* feat = (const float*)d_in[0];
    const int*   mask = (const int*)d_in[1];
    const float* Wq = (const float*)d_in[2];
    const float* bq = (const float*)d_in[3];
    const float* Wk = (const float*)d_in[4];
    const float* bk = (const float*)d_in[5];
    const float* Wv = (const float*)d_in[6];
    const float* bv = (const float*)d_in[7];

    bf16* ws = (bf16*)d_ws;

    convert_in<<<7171, 256, 0, stream>>>(feat, Wq, Wk, Wv, bq, bk, bv, ws);

    dim3 g1(32, 8, 2);
    qkv_gemm<<<g1, 256, 0, stream>>>(ws, ws, mask);

    dim3 g2(2 * NHEAD, SEQ_L / 128);
    attn_kernel<<<g2, 512, 0, stream>>>(ws, mask, (float*)d_out);
}

// Round 14
// 161.390 us; speedup vs baseline: 1.9447x; 1.9447x over previous
//
#include <hip/hip_runtime.h>

typedef __bf16 bf16;
typedef __attribute__((ext_vector_type(4))) __bf16 bf16x4;
typedef __attribute__((ext_vector_type(8))) __bf16 bf16x8;
typedef __attribute__((ext_vector_type(4))) float f32x4;
typedef __attribute__((ext_vector_type(16))) float f32x16;
typedef unsigned int u32;

#define D_MODEL 1024
#define SEQ_L   2048
#define NHEAD   16
#define HDIM    64
#define MROWS   4096   // B*L

// 1/sqrt(64) * log2(e): folded into Wq/bq so attn can use raw v_exp_f32 (exp2)
#define S_SCALE 0.18033688f

// ---- workspace layout (bf16-element offsets) ----
#define FEAT_OFF  512u
#define WQ_OFF    (FEAT_OFF + 4194304u)
#define WK_OFF    (WQ_OFF + 1048576u)
#define WV_OFF    (WK_OFF + 1048576u)
#define BQ_OFF    (WV_OFF + 1048576u)
#define BK_OFF    (BQ_OFF + 1024u)
#define BV_OFF    (BK_OFF + 1024u)
#define Q_OFF     (BV_OFF + 1024u)
#define K_OFF     (Q_OFF + 4194304u)
#define V_OFF     (K_OFF + 4194304u)     // Vt: [b][dout(1024)][token(2048)]

// async global->LDS, 16B per lane; LDS dest = wave-uniform base + lane*16
typedef const __attribute__((address_space(1))) u32* gp_t;
typedef __attribute__((address_space(3))) u32* lp_t;
__device__ __forceinline__ void ld16(const bf16* g, bf16* l) {
    __builtin_amdgcn_global_load_lds((gp_t)g, (lp_t)l, 16, 0, 0);
}

// ---------------------------------------------------------------------------
// Convert f32 inputs -> bf16 in ws. Wq/bq pre-scaled by S_SCALE (exact-count
// rounding: one f32->bf16 round either way). Flat grid: 7171 x 256 x 4.
// ---------------------------------------------------------------------------
__global__ void convert_in(const float* __restrict__ feat,
                           const float* __restrict__ wq, const float* __restrict__ wk,
                           const float* __restrict__ wv,
                           const float* __restrict__ bq, const float* __restrict__ bk,
                           const float* __restrict__ bv,
                           bf16* __restrict__ ws) {
    const int bid = blockIdx.x;
    const float* src; bf16* dst; int off; float sc = 1.0f;
    if (bid < 4096)      { src = feat; dst = ws + FEAT_OFF; off = bid * 1024; }
    else if (bid < 5120) { src = wq;   dst = ws + WQ_OFF;   off = (bid - 4096) * 1024; sc = S_SCALE; }
    else if (bid < 6144) { src = wk;   dst = ws + WK_OFF;   off = (bid - 5120) * 1024; }
    else if (bid < 7168) { src = wv;   dst = ws + WV_OFF;   off = (bid - 6144) * 1024; }
    else if (bid == 7168){ src = bq;   dst = ws + BQ_OFF;   off = 0; sc = S_SCALE; }
    else if (bid == 7169){ src = bk;   dst = ws + BK_OFF;   off = 0; }
    else                 { src = bv;   dst = ws + BV_OFF;   off = 0; }
    int idx = off + threadIdx.x * 4;
    float4 v = *(const float4*)(src + idx);
    bf16x4 o;
    o[0] = (bf16)(v.x * sc);
    o[1] = (bf16)(v.y * sc);
    o[2] = (bf16)(v.z * sc);
    o[3] = (bf16)(v.w * sc);
    *(bf16x4*)(dst + idx) = o;          // one 8B store (coalesced)
}

// ---------------------------------------------------------------------------
// QKV projection v3 (rounds 8+11): Q,K fused with BK=32 double-buffered
// prefetch; zi=1: Vt = Wv*X^T with BK=64 double-buffered.
// Grid (32,8,2) = 512 blocks, 64KB LDS -> 2 blocks/CU.
// ---------------------------------------------------------------------------
__global__ __launch_bounds__(256, 2) void qkv_gemm(const bf16* __restrict__ ws,
                                                   bf16* __restrict__ wsw,
                                                   const int* __restrict__ mask) {
    __shared__ bf16 smem[32768];               // 64KB pool
    const int zi   = blockIdx.z;
    const int t    = threadIdx.x;
    const int lane = t & 63;
    const int wave = t >> 6;
    const int quad = lane >> 4;
    const int l16  = lane & 15;
    const int wrow = (wave >> 1) * 64;
    const int wcol = (wave & 1) * 64;

    if (zi == 0) {
        // ================= fused Q,K (BK=32, double-buffered) =================
        bf16* Ab = smem;                       // + buf*4096
        bf16* Bq = smem + 8192;
        bf16* Bk = smem + 16384;
        const bf16* X   = ws + FEAT_OFF;
        const bf16* Wq  = ws + WQ_OFF;         // pre-scaled by S_SCALE
        const bf16* Wk  = ws + WK_OFF;
        const int m0 = blockIdx.x * 128;       // token rows
        const int n0 = blockIdx.y * 128;       // output cols

        const int r4  = lane >> 2;             // row-in-chunk 0..15
        const int sgq = (lane & 3) ^ ((lane >> 3) & 3);   // pre-swizzled seg

        f32x4 aq[4][4], ak[4][4];
        for (int mi = 0; mi < 4; ++mi)
            for (int ni = 0; ni < 4; ++ni) {
                aq[mi][ni] = (f32x4){0.f, 0.f, 0.f, 0.f};
                ak[mi][ni] = (f32x4){0.f, 0.f, 0.f, 0.f};
            }

#define STAGEQK(bb, k0)                                                        \
    do {                                                                       \
        _Pragma("unroll")                                                      \
        for (int i = 0; i < 2; ++i) {                                          \
            int ch  = wave * 2 + i;                                            \
            int row = ch * 16 + r4;                                            \
            ld16(X  + (size_t)(m0 + row) * D_MODEL + (k0) + sgq * 8,           \
                 Ab + (bb) * 4096 + ch * 512);                                 \
            ld16(Wq + (size_t)(n0 + row) * D_MODEL + (k0) + sgq * 8,           \
                 Bq + (bb) * 4096 + ch * 512);                                 \
            ld16(Wk + (size_t)(n0 + row) * D_MODEL + (k0) + sgq * 8,           \
                 Bk + (bb) * 4096 + ch * 512);                                 \
        }                                                                      \
    } while (0)

        STAGEQK(0, 0);
        __syncthreads();

        int cur = 0;
        for (int k0 = 0; k0 < D_MODEL; k0 += 32) {
            // prefetch next step FIRST (in flight under the 32 MFMAs below)
            if (k0 + 32 < D_MODEL) STAGEQK(cur ^ 1, k0 + 32);

            bf16x8 af[4], bq8[4], bk8[4];
#pragma unroll
            for (int mi = 0; mi < 4; ++mi) {
                int row  = wrow + mi * 16 + l16;
                int phys = quad ^ ((row >> 1) & 3);
                af[mi] = *(const bf16x8*)(&Ab[cur * 4096 + row * 32 + phys * 8]);
            }
#pragma unroll
            for (int ni = 0; ni < 4; ++ni) {
                int row  = wcol + ni * 16 + l16;
                int phys = quad ^ ((row >> 1) & 3);
                bq8[ni] = *(const bf16x8*)(&Bq[cur * 4096 + row * 32 + phys * 8]);
                bk8[ni] = *(const bf16x8*)(&Bk[cur * 4096 + row * 32 + phys * 8]);
            }
#pragma unroll
            for (int mi = 0; mi < 4; ++mi)
#pragma unroll
                for (int ni = 0; ni < 4; ++ni)
                    aq[mi][ni] = __builtin_amdgcn_mfma_f32_16x16x32_bf16(
                        af[mi], bq8[ni], aq[mi][ni], 0, 0, 0);
#pragma unroll
            for (int mi = 0; mi < 4; ++mi)
#pragma unroll
                for (int ni = 0; ni < 4; ++ni)
                    ak[mi][ni] = __builtin_amdgcn_mfma_f32_16x16x32_bf16(
                        af[mi], bk8[ni], ak[mi][ni], 0, 0, 0);

            __syncthreads();    // joins + drains the in-flight prefetch
            cur ^= 1;
        }
#undef STAGEQK

        bf16* Yq = wsw + Q_OFF;
        bf16* Yk = wsw + K_OFF;
        const bf16* bq = ws + BQ_OFF;
        const bf16* bk = ws + BK_OFF;
#pragma unroll
        for (int ni = 0; ni < 4; ++ni) {
            int col = n0 + wcol + ni * 16 + l16;
            float bqf = (float)bq[col];
            float bkf = (float)bk[col];
#pragma unroll
            for (int mi = 0; mi < 4; ++mi) {
                int rowb = m0 + wrow + mi * 16 + quad * 4;
#pragma unroll
                for (int r = 0; r < 4; ++r) {
                    Yq[(size_t)(rowb + r) * D_MODEL + col] = (bf16)(aq[mi][ni][r] + bqf);
                    float v = ak[mi][ni][r] + bkf;
                    if (mask[rowb + r] == 0) v = 0.f;             // zero masked K rows
                    Yk[(size_t)(rowb + r) * D_MODEL + col] = (bf16)v;
                }
            }
        }
    } else {
        // ================= Vt = Wv*X^T (BK=64, double-buffered) ==============
        bf16* Ab = smem;                       // + buf*8192
        bf16* Bb = smem + 16384;
        const bf16* Amat = ws + WV_OFF;
        const bf16* Bmat = ws + FEAT_OFF;
        const bf16* bias = ws + BV_OFF;
        bf16* Y = wsw + V_OFF;
        const int m0 = blockIdx.y * 128;       // dout rows
        const int n0 = blockIdx.x * 128;       // token cols

        const int r8 = lane >> 3;
        const int sl = lane & 7;
        const int sg = sl ^ r8;

        f32x4 acc[4][4];
        for (int mi = 0; mi < 4; ++mi)
            for (int ni = 0; ni < 4; ++ni)
                acc[mi][ni] = (f32x4){0.f, 0.f, 0.f, 0.f};

#define STAGEV(bb, k0)                                                         \
    do {                                                                       \
        _Pragma("unroll")                                                      \
        for (int i = 0; i < 4; ++i) {                                          \
            int ch  = wave * 4 + i;                                            \
            int row = ch * 8 + r8;                                             \
            ld16(Amat + (size_t)(m0 + row) * D_MODEL + (k0) + sg * 8,          \
                 Ab + (bb) * 8192 + ch * 512);                                 \
            ld16(Bmat + (size_t)(n0 + row) * D_MODEL + (k0) + sg * 8,          \
                 Bb + (bb) * 8192 + ch * 512);                                 \
        }                                                                      \
    } while (0)

        STAGEV(0, 0);
        __syncthreads();

        int cur = 0;
        for (int k0 = 0; k0 < D_MODEL; k0 += 64) {
            if (k0 + 64 < D_MODEL) STAGEV(cur ^ 1, k0 + 64);

#pragma unroll
            for (int kk = 0; kk < 2; ++kk) {
                const int sgb = quad + kk * 4;
                bf16x8 af[4], bfr[4];
#pragma unroll
                for (int mi = 0; mi < 4; ++mi) {
                    int row = wrow + mi * 16 + l16;
                    af[mi] = *(const bf16x8*)(
                        &Ab[cur * 8192 + row * 64 + ((sgb ^ (row & 7)) << 3)]);
                }
#pragma unroll
                for (int ni = 0; ni < 4; ++ni) {
                    int row = wcol + ni * 16 + l16;
                    bfr[ni] = *(const bf16x8*)(
                        &Bb[cur * 8192 + row * 64 + ((sgb ^ (row & 7)) << 3)]);
                }
#pragma unroll
                for (int mi = 0; mi < 4; ++mi)
#pragma unroll
                    for (int ni = 0; ni < 4; ++ni)
                        acc[mi][ni] = __builtin_amdgcn_mfma_f32_16x16x32_bf16(
                            af[mi], bfr[ni], acc[mi][ni], 0, 0, 0);
            }

            __syncthreads();    // joins + drains the in-flight prefetch
            cur ^= 1;
        }
#undef STAGEV

#pragma unroll
        for (int mi = 0; mi < 4; ++mi) {
#pragma unroll
            for (int r = 0; r < 4; ++r) {
                int rowv = m0 + wrow + mi * 16 + quad * 4 + r;   // dout
                float bvf = (float)bias[rowv];
#pragma unroll
                for (int ni = 0; ni < 4; ++ni) {
                    int col = n0 + wcol + ni * 16 + l16;          // token
                    float v = acc[mi][ni][r] + bvf;
                    if (mask[col] == 0) v = 0.f;                  // zero masked Vt cols
                    size_t addr = (size_t)(col >> 11) * 2097152u +
                                  (size_t)rowv * 2048u + (col & 2047);
                    Y[addr] = (bf16)v;
                }
            }
        }
    }
}

// ---------------------------------------------------------------------------
// Flash attention v17 (round-12 best: attn 48.9us, RESTORED VERBATIM).
// In-block key-split (qh = wave&3, kh = wave>>2) + mask-hoist (zero vmem
// consumers in the k-loop) + T5 setprio on MFMA clusters. Round-13's K-to-
// register variant spilled (launch_bounds(512,4) => hard 64-VGPR cap; +64
// VGPR of K regs can never fit) — K stays in LDS. This operating point
// (64 VGPR / 16 waves/CU / 64KB LDS) measured best across 13 rounds; all
// structural escapes (more ILP, no-LDS, cross-iter pipeline, reg-K) lost.
// grid (bh, qt) = (32, 16) = 512 blocks x 512 thr.
// ---------------------------------------------------------------------------
__global__ __launch_bounds__(512, 4) void attn_kernel(
    const bf16* __restrict__ ws,
    const int* __restrict__ mask, float* __restrict__ out) {
    const int bh  = blockIdx.x;          // 0..31
    const int qt  = blockIdx.y;          // 0..15 (128 q-rows per block)
    const int b   = bh >> 4, h = bh & 15;
    const int t    = threadIdx.x;
    const int lane = t & 63;
    const int wave = t >> 6;            // 0..7
    const int qh   = wave & 3;          // q sub-tile within block
    const int kh   = wave >> 2;         // key half
    const int half = lane >> 5;
    const int l31  = lane & 31;
    const int kt0  = kh * 1024;

    __shared__ bf16 smem[32768];        // 64KB: K[kh][buf][4096] | V[kh][buf][4096]
    bf16* Kb = smem;                    // K(kh,buf) = Kb + (kh*2+buf)*4096
    bf16* Vb = smem + 16384;            // V(kh,buf) = Vb + (kh*2+buf)*4096

    const bf16* Qh  = ws + Q_OFF + (size_t)(b * SEQ_L) * D_MODEL + h * HDIM;
    const bf16* Kh  = ws + K_OFF + (size_t)(b * SEQ_L) * D_MODEL + h * HDIM;
    const bf16* Vth = ws + V_OFF + (size_t)b * 2097152u + (size_t)(h * HDIM) * SEQ_L;

    // ---- mask loads FIRST (in-order VMEM: consuming them later won't drain
    //      the staging ld16s issued after)
    int mvv[16];
#pragma unroll
    for (int i = 0; i < 16; ++i)
        mvv[i] = mask[b * SEQ_L + kt0 + i * 64 + lane];

    // staging geometry (qh plays v9's wave role inside the kh-group)
    const int srow = (lane >> 3);            // 0..7
    const int sg   = (lane & 7) ^ srow;      // swizzled global segment

#define STAGE(bb, kt)                                                          \
    do {                                                                       \
        _Pragma("unroll")                                                      \
        for (int i = 0; i < 2; ++i) {                                          \
            int row = i * 32 + qh * 8 + srow;                                  \
            ld16(Kh + (size_t)((kt) + row) * D_MODEL + sg * 8,                 \
                 Kb + (kh * 2 + (bb)) * 4096 + i * 2048 + qh * 512);           \
            ld16(Vth + (size_t)row * SEQ_L + (kt) + sg * 8,                    \
                 Vb + (kh * 2 + (bb)) * 4096 + i * 2048 + qh * 512);           \
        }                                                                      \
    } while (0)

    // prologue: each kh-group fills its buffer 0
    STAGE(0, kt0);

    // ---- masked-key overcount (tile-order independent), consumed pre-loop
    int nm = 0;
#pragma unroll
    for (int i = 0; i < 16; ++i)
        nm += (int)__popcll(__ballot(mvv[i] != 0));

    // Q fragments as B-operand (n=q=l31, k=d); scale already folded into Wq.
    const int qrow0 = qt * 128 + qh * 32;
    bf16x8 qf[4];
#pragma unroll
    for (int ks = 0; ks < 4; ++ks)
        qf[ks] = *(const bf16x8*)(Qh + (size_t)(qrow0 + l31) * D_MODEL
                                  + ks * 16 + half * 8);

    bf16x8 ones;
#pragma unroll
    for (int j = 0; j < 8; ++j) ones[j] = (bf16)1.0f;

    f32x16 o[2], lacc;
#pragma unroll
    for (int i = 0; i < 16; ++i) { o[0][i] = 0.f; o[1][i] = 0.f; lacc[i] = 0.f; }

    __syncthreads();

    int cur = 0;
    for (int it = 0; it < 16; ++it) {
        const int kt = kt0 + it * 64;
        // ---- issue next-tile prefetch FIRST; no vmem consumer below, so it
        //      stays in flight across the whole QK->exp->PV body
        if (it < 15) STAGE(cur ^ 1, kt + 64);

        // ---- S^T = K * Q^T : D[key-rows][q-cols]  (Q pre-scaled)
        const bf16* Kcur = Kb + (kh * 2 + cur) * 4096;
        f32x16 st[2];
        __builtin_amdgcn_s_setprio(1);
#pragma unroll
        for (int ktile = 0; ktile < 2; ++ktile) {
#pragma unroll
            for (int i = 0; i < 16; ++i) st[ktile][i] = 0.f;
#pragma unroll
            for (int ks = 0; ks < 4; ++ks) {
                const int row  = ktile * 32 + l31;
                const int slot = (ks * 2 + half) ^ (l31 & 7);
                bf16x8 kf = *(const bf16x8*)(&Kcur[row * 64 + slot * 8]);
                st[ktile] = __builtin_amdgcn_mfma_f32_32x32x16_bf16(
                    kf, qf[ks], st[ktile], 0, 0, 0);
            }
        }
        __builtin_amdgcn_s_setprio(0);

        // ---- P = exp2(S^T); masked keys give st=0 -> p=1 (corrected in l)
        bf16x4 pk[2][4];
#pragma unroll
        for (int ktile = 0; ktile < 2; ++ktile) {
#pragma unroll
            for (int g = 0; g < 4; ++g) {
                bf16x4 pkv;
#pragma unroll
                for (int j = 0; j < 4; ++j)
                    pkv[j] = (bf16)__builtin_amdgcn_exp2f(st[ktile][g * 4 + j]);
                pk[ktile][g] = pkv;
            }
        }

        // ---- C->A layout via one shfl_xor(32) per fragment
        bf16x8 pf[4];
#pragma unroll
        for (int ks = 0; ks < 4; ++ks) {
            const int k1 = ks & 1, kt2 = ks >> 1;
            uint2 a  = __builtin_bit_cast(uint2, pk[kt2][2 * k1]);
            uint2 bb = __builtin_bit_cast(uint2, pk[kt2][2 * k1 + 1]);
            uint2 keep, send;
            keep.x = half ? bb.x : a.x;  keep.y = half ? bb.y : a.y;
            send.x = half ? a.x : bb.x;  send.y = half ? a.y : bb.y;
            uint2 recv;
            recv.x = (unsigned)__shfl_xor((int)send.x, 32);
            recv.y = (unsigned)__shfl_xor((int)send.y, 32);
            uint4 frag;
            frag.x = half ? recv.x : keep.x;
            frag.y = half ? recv.y : keep.y;
            frag.z = half ? keep.x : recv.x;
            frag.w = half ? keep.y : recv.y;
            pf[ks] = __builtin_bit_cast(bf16x8, frag);
        }

        // ---- O += P * V ; l += P * ones (row-sums on the MFMA pipe)
        const bf16* Vcur = Vb + (kh * 2 + cur) * 4096;
        __builtin_amdgcn_s_setprio(1);
#pragma unroll
        for (int ks = 0; ks < 4; ++ks)
            lacc = __builtin_amdgcn_mfma_f32_32x32x16_bf16(pf[ks], ones, lacc, 0, 0, 0);
#pragma unroll
        for (int dt = 0; dt < 2; ++dt) {
#pragma unroll
            for (int ks = 0; ks < 4; ++ks) {
                const int row  = dt * 32 + l31;
                const int slot = (ks * 2 + half) ^ (l31 & 7);
                bf16x8 vf = *(const bf16x8*)(&Vcur[row * 64 + slot * 8]);
                o[dt] = __builtin_amdgcn_mfma_f32_32x32x16_bf16(
                    pf[ks], vf, o[dt], 0, 0, 0);
            }
        }
        __builtin_amdgcn_s_setprio(0);

        // joins waves AND drains the in-flight prefetch (vmcnt(0) before barrier)
        __syncthreads();
        cur ^= 1;
    }
#undef STAGE

    // ---- in-block cross-half reduction (replaces the combine kernel).
    //      K/V buffers are dead after the loop's final barrier; reuse as a
    //      [48][256] f32 exchange (lanes contiguous -> conflict-free).
    const float corr = (float)(1024 - nm);
    float* ex = (float*)smem;
    const int slot = qh * 64 + lane;
    if (kh == 1) {
#pragma unroll
        for (int r = 0; r < 16; ++r) {
            ex[r * 256 + slot]        = o[0][r];
            ex[(16 + r) * 256 + slot] = o[1][r];
            ex[(32 + r) * 256 + slot] = lacc[r] - corr;   // l-partial, corr folded
        }
    }
    __syncthreads();
    if (kh == 0) {
#pragma unroll
        for (int r = 0; r < 16; ++r) {
            const int q32 = (r & 3) + 8 * (r >> 2) + 4 * half;
            const int q = qrow0 + q32;
            const size_t base = ((size_t)(b * SEQ_L + q)) * D_MODEL + h * HDIM;
            const float l  = (lacc[r] - corr) + ex[(32 + r) * 256 + slot];
            const float rl = 1.0f / fmaxf(l, 1e-30f);
            out[base + l31]      = (o[0][r] + ex[r * 256 + slot]) * rl;
            out[base + 32 + l31] = (o[1][r] + ex[(16 + r) * 256 + slot]) * rl;
        }
    }
}

extern "C" void kernel_launch(void* const* d_in, const int* in_sizes, int n_in,
                              void* d_out, int out_size, void* d_ws, size_t ws_size,
                              hipStream_t stream) {
    const float* feat = (const float*)d_in[0];
    const int*   mask = (const int*)d_in[1];
    const float* Wq = (const float*)d_in[2];
    const float* bq = (const float*)d_in[3];
    const float* Wk = (const float*)d_in[4];
    const float* bk = (const float*)d_in[5];
    const float* Wv = (const float*)d_in[6];
    const float* bv = (const float*)d_in[7];

    bf16* ws = (bf16*)d_ws;

    convert_in<<<7171, 256, 0, stream>>>(feat, Wq, Wk, Wv, bq, bk, bv, ws);

    dim3 g1(32, 8, 2);
    qkv_gemm<<<g1, 256, 0, stream>>>(ws, ws, mask);

    dim3 g2(2 * NHEAD, SEQ_L / 128);
    attn_kernel<<<g2, 512, 0, stream>>>(ws, mask, (float*)d_out);
}